// Round 1
// baseline (2576.147 us; speedup 1.0000x reference)
//
#include <hip/hip_runtime.h>
#include <hip/hip_bf16.h>
#include <stdint.h>

// ContinuousActorCritic: B=256, T=2048, I=128, H=256, A=8
#define BB 256
#define TT 2048
#define II 128
#define HH 256
#define XPLD 260   // s_xp row stride (floats); 256+4 pad splits quad bank collisions on writes

typedef _Float16       f16x8     __attribute__((ext_vector_type(8)));  // 4 VGPR
typedef float          f32x4     __attribute__((ext_vector_type(4)));
typedef unsigned short ushort8_t __attribute__((ext_vector_type(8)));
typedef float          float4_t  __attribute__((ext_vector_type(4)));

__device__ __forceinline__ float bf2f(unsigned short u) {
    union { unsigned int i; float f; } v; v.i = ((unsigned int)u) << 16; return v.f;
}

// One block per batch row; 256 threads = 4 waves, 1 wave/SIMD.
// Wave w owns outputs [w*64, w*64+64) as 4 MFMA N-tiles. h state fp32 in regs,
// published per-step to LDS as hi/lo-split f16 (22-bit mantissa ~ fp32) because
// the recurrence amplifies operand rounding 1e3-1e4x over 2048 steps.
//
// NEW vs previous round: the x-projection W_ih@x_t no longer rides the per-step
// MFMAs (16/step broadcast across the wasted M dim). Instead the 16 M rows
// batch 16 TIMESTEPS: per 16-step chunk, 16 MFMAs/wave compute xp[t'][j] for
// the whole chunk (1 MFMA/step amortized vs 16), staged to s_xp (dbuf) and
// consumed as one fp32 ds_read + add per step. Per-step MFMA: 80 -> 64.
__global__ __launch_bounds__(256, 1)
void rnn_mfma_xp(const void* __restrict__ xv,  const void* __restrict__ hxv,
                 const void* __restrict__ Wihv, const void* __restrict__ Whhv,
                 const void* __restrict__ Wactv, const void* __restrict__ Wcritv,
                 void* __restrict__ outv)
{
    const int b    = blockIdx.x;
    const int tid  = threadIdx.x;
    const int w    = tid >> 6;
    const int l    = tid & 63;
    const int quad = l >> 4;
    const int col  = l & 15;
    const int jown = w * 64 + l;          // == tid

    __shared__ __align__(16) _Float16 s_hhi[2][HH];      // h_hi operand, dbuf
    __shared__ __align__(16) _Float16 s_hlo[2][HH];      // h_lo*2048 operand, dbuf
    __shared__ __align__(16) float    s_xp[2][16 * XPLD];// xproj chunk, dbuf
    __shared__ float s_hf[HH];                           // final h fp32 (heads)
    __shared__ int s_flag;

    // ---- storage-dtype detector (R3-proven; bf16 expected) ----
    if (tid == 0) {
        const unsigned short* p = (const unsigned short*)Whhv;
        int cnt = 0;
        for (int i = 0; i < 256; ++i) { int e = (p[i] >> 7) & 0xFF; cnt += (e > 128) ? 1 : 0; }
        s_flag = (cnt > 16) ? 1 : 0;   // 1 => fp32 storage
    }
    __syncthreads();
    const bool f32io = (s_flag != 0);

    // ---- B-fragments, register-stationary, f16 (bf16->f16 exact) ----
    // bfrag[c*4+t]: lane holds W(j, k0..k0+7), j = w*64 + t*16 + col,
    // k0 = 32c + quad*8.  c 0..7: W_hh (k<256); c 8..11: W_ih (xproj only now).
    f16x8 bfrag[48];
#pragma unroll
    for (int c = 0; c < 12; ++c) {
#pragma unroll
        for (int t = 0; t < 4; ++t) {
            const int j  = w * 64 + t * 16 + col;
            const int k0 = 32 * c + quad * 8;
            f16x8 bv;
            if (!f32io) {
                const unsigned short* src = (k0 < HH)
                    ? ((const unsigned short*)Whhv + j * HH + k0)
                    : ((const unsigned short*)Wihv + j * II + (k0 - HH));
                ushort8_t u = *(const ushort8_t*)src;
#pragma unroll
                for (int e = 0; e < 8; ++e) bv[e] = (_Float16)bf2f(u[e]);
            } else {
                const float* src = (k0 < HH)
                    ? ((const float*)Whhv + j * HH + k0)
                    : ((const float*)Wihv + j * II + (k0 - HH));
#pragma unroll
                for (int e = 0; e < 8; ++e) bv[e] = (_Float16)src[e];
            }
            bfrag[c * 4 + t] = bv;
        }
    }

    const f32x4 kz = {0.f, 0.f, 0.f, 0.f};

    // ---- xproj chunk-prep machinery ----
    // A-frag layout (matches verified per-step usage): row m = lane&15,
    // k = (lane>>4)*8 + e.  Here m = timestep-in-chunk, k = input index.
    ushort8_t xru[4];   // raw bf16 prefetch
    float4_t  xrf[8];   // raw fp32 prefetch
    f16x8     xaf[4];   // converted A-frags

    auto xload = [&](int tbase) {
        if (!f32io) {
            const unsigned short* gp = (const unsigned short*)xv
                + ((size_t)b * TT + tbase + col) * II + quad * 8;
#pragma unroll
            for (int c = 0; c < 4; ++c) xru[c] = *(const ushort8_t*)(gp + 32 * c);
        } else {
            const float* gp = (const float*)xv
                + ((size_t)b * TT + tbase + col) * II + quad * 8;
#pragma unroll
            for (int c = 0; c < 4; ++c) {
                xrf[2 * c]     = *(const float4_t*)(gp + 32 * c);
                xrf[2 * c + 1] = *(const float4_t*)(gp + 32 * c + 4);
            }
        }
    };
    auto xcvt = [&]() {
        if (!f32io) {
#pragma unroll
            for (int c = 0; c < 4; ++c)
#pragma unroll
                for (int e = 0; e < 8; ++e) xaf[c][e] = (_Float16)bf2f(xru[c][e]);
        } else {
#pragma unroll
            for (int c = 0; c < 4; ++c)
#pragma unroll
                for (int e = 0; e < 8; ++e) xaf[c][e] = (_Float16)xrf[2 * c + (e >> 2)][e & 3];
        }
    };
    auto xmm = [&](float* dst) {
        f32x4 xa[4];
#pragma unroll
        for (int tt = 0; tt < 4; ++tt) xa[tt] = kz;
#pragma unroll
        for (int c = 0; c < 4; ++c)
#pragma unroll
            for (int tt = 0; tt < 4; ++tt)
                xa[tt] = __builtin_amdgcn_mfma_f32_16x16x32_f16(xaf[c], bfrag[32 + c * 4 + tt], xa[tt], 0, 0, 0);
        // D layout: col = lane&15 (-> j), row = (lane>>4)*4 + r (-> t')
#pragma unroll
        for (int tt = 0; tt < 4; ++tt)
#pragma unroll
            for (int r = 0; r < 4; ++r)
                dst[(quad * 4 + r) * XPLD + w * 64 + tt * 16 + col] = xa[tt][r];
    };

    // ---- init h (fp32 state; publish hi/lo operand) ----
    float hreg;
    {
        if (!f32io) hreg = bf2f(((const unsigned short*)hxv)[b * HH + jown]);
        else        hreg = ((const float*)hxv)[b * HH + jown];
        _Float16 hi = (_Float16)hreg;
        _Float16 lo = (_Float16)((hreg - (float)hi) * 2048.f);
        s_hhi[0][jown] = hi;
        s_hlo[0][jown] = lo;
    }

    // ---- prologue: xproj for chunk 0 ----
    xload(0); xcvt(); xmm(&s_xp[0][0]);
    __syncthreads();

    for (int t = 0; t < TT; ++t) {
        const int par   = t & 1;
        const int slot  = (t >> 4) & 1;
        const int slice = t & 15;
        const int tn    = (t & ~15) + 16;       // next chunk base
        const bool prep = (tn < TT);

        // chunk n+1 prep pipeline: load @slice0, cvt @slice1, mfma+store @slice2
        if (slice == 0 && prep) xload(tn);

        const float xp = s_xp[slot][slice * XPLD + jown];   // issued early, used late

        const _Float16* hbh = s_hhi[par];
        const _Float16* hbl = s_hlo[par];

        if (slice == 1 && prep) xcvt();
        if (slice == 2 && prep) xmm(&s_xp[slot ^ 1][0]);

        f32x4 acch[4], accl[4];
        {   // c = 0, seed with persistent zero (no explicit acc-init pass)
            f16x8 a = *(const f16x8*)(hbh + quad * 8);
#pragma unroll
            for (int tt = 0; tt < 4; ++tt)
                acch[tt] = __builtin_amdgcn_mfma_f32_16x16x32_f16(a, bfrag[tt], kz, 0, 0, 0);
        }
#pragma unroll
        for (int c = 1; c < 8; ++c) {           // h_hi part: k = 32c + quad*8
            f16x8 a = *(const f16x8*)(hbh + 32 * c + quad * 8);
#pragma unroll
            for (int tt = 0; tt < 4; ++tt)
                acch[tt] = __builtin_amdgcn_mfma_f32_16x16x32_f16(a, bfrag[c * 4 + tt], acch[tt], 0, 0, 0);
        }
        {   // lo, c = 0
            f16x8 a = *(const f16x8*)(hbl + quad * 8);
#pragma unroll
            for (int tt = 0; tt < 4; ++tt)
                accl[tt] = __builtin_amdgcn_mfma_f32_16x16x32_f16(a, bfrag[tt], kz, 0, 0, 0);
        }
#pragma unroll
        for (int c = 1; c < 8; ++c) {           // h_lo part (same weights)
            f16x8 a = *(const f16x8*)(hbl + 32 * c + quad * 8);
#pragma unroll
            for (int tt = 0; tt < 4; ++tt)
                accl[tt] = __builtin_amdgcn_mfma_f32_16x16x32_f16(a, bfrag[c * 4 + tt], accl[tt], 0, 0, 0);
        }

        // all 16 D-rows identical; lane l takes tile=quad, col, reg 0
        float ph = (quad & 2) ? ((quad & 1) ? acch[3][0] : acch[2][0])
                              : ((quad & 1) ? acch[1][0] : acch[0][0]);
        float pl = (quad & 2) ? ((quad & 1) ? accl[3][0] : accl[2][0])
                              : ((quad & 1) ? accl[1][0] : accl[0][0]);
        float pre = (ph + xp) + pl * (1.f / 2048.f);   // x added adjacent to hi chain (old order)

        hreg = 0.8f * hreg + 0.2f * fmaxf(pre, 0.f);

        _Float16 hi = (_Float16)hreg;
        _Float16 lo = (_Float16)((hreg - (float)hi) * 2048.f);
        s_hhi[par ^ 1][jown] = hi;
        s_hlo[par ^ 1][jown] = lo;

        if (t == TT - 1) s_hf[jown] = hreg;     // publish fp32 h for heads
        __syncthreads();
    }

    // ---- epilogue ----
    // new_hx: out[2304 + b*256 + j] (fp32 state)
    if (!f32io) ((__hip_bfloat16*)outv)[2304 + b * HH + jown] = __float2bfloat16(hreg);
    else        ((float*)outv)[2304 + b * HH + jown] = hreg;

    // actor_logits out[b*8 + a], critic out[2048 + b]
    if (tid < 9) {
        float acc = 0.f;
        if (!f32io) {
            const unsigned short* wr = (tid < 8) ? ((const unsigned short*)Wactv + tid * HH)
                                                 : (const unsigned short*)Wcritv;
            for (int i = 0; i < HH; ++i) acc += bf2f(wr[i]) * s_hf[i];
        } else {
            const float* wr = (tid < 8) ? ((const float*)Wactv + tid * HH)
                                        : (const float*)Wcritv;
            for (int i = 0; i < HH; ++i) acc += wr[i] * s_hf[i];
        }
        const int idx = (tid < 8) ? (b * 8 + tid) : (2048 + b);
        if (!f32io) ((__hip_bfloat16*)outv)[idx] = __float2bfloat16(acc);
        else        ((float*)outv)[idx] = acc;
    }
}

extern "C" void kernel_launch(void* const* d_in, const int* in_sizes, int n_in,
                              void* d_out, int out_size, void* d_ws, size_t ws_size,
                              hipStream_t stream) {
    // dict order: x [256,2048,128], hx [1,256,256], W_ih [256,128],
    //             W_hh [256,256], W_actor [8,256], W_critic [1,256]
    rnn_mfma_xp<<<dim3(BB), dim3(256), 0, stream>>>(
        d_in[0], d_in[1], d_in[2], d_in[3], d_in[4], d_in[5], d_out);
}

// Round 2
// 2180.999 us; speedup vs baseline: 1.1812x; 1.1812x over previous
//
#include <hip/hip_runtime.h>
#include <hip/hip_bf16.h>
#include <stdint.h>

// ContinuousActorCritic: B=256, T=2048, I=128, H=256, A=8
#define BB 256
#define TT 2048
#define II 128
#define HH 256
#define XPLD 260   // s_xp row stride (floats); 256+4 pad keeps write conflicts at free 2-way

typedef _Float16       f16x8     __attribute__((ext_vector_type(8)));  // 4 VGPR
typedef float          f32x4     __attribute__((ext_vector_type(4)));
typedef unsigned short ushort8_t __attribute__((ext_vector_type(8)));
typedef float          float4_t  __attribute__((ext_vector_type(4)));

__device__ __forceinline__ float bf2f(unsigned short u) {
    union { unsigned int i; float f; } v; v.i = ((unsigned int)u) << 16; return v.f;
}

// R2: 512 threads = 8 waves = 2 waves/SIMD (R1 post-mortem: with 1 wave/SIMD the
// per-step serial overhead (~1800 cy: ds_read latency, MFMA tail, vmcnt, barrier)
// is fully exposed; MfmaUtil fell to 38% after removing x-MFMAs. A sibling wave
// per SIMD hides those stalls; per-SIMD MFMA issue stays ~66/step.)
// Wave w owns outputs [w*32, w*32+32) as 2 MFMA N-tiles -> bfrag = 24 frags
// (96 VGPR), two waves fit the 256-VGPR budget. Lanes 32-63 duplicate 0-31.
// h state fp32 in regs; published per-step as hi/lo-split f16 (22-bit mantissa)
// because the recurrence amplifies operand rounding 1e3-1e4x over 2048 steps.
// xproj batched per 16-step chunk via MFMA M-dim = timesteps (1 MFMA/step
// amortized vs 16), staged to s_xp dbuf; prep spread: load@0, cvt@4, mfma@8.
__global__ __launch_bounds__(512, 2)
void rnn_mfma_w8(const void* __restrict__ xv,  const void* __restrict__ hxv,
                 const void* __restrict__ Wihv, const void* __restrict__ Whhv,
                 const void* __restrict__ Wactv, const void* __restrict__ Wcritv,
                 void* __restrict__ outv)
{
    const int b    = blockIdx.x;
    const int tid  = threadIdx.x;
    const int w    = tid >> 6;            // 0..7
    const int l    = tid & 63;
    const int quad = l >> 4;
    const int col  = l & 15;
    const int tsel = (l >> 4) & 1;        // which N-tile this lane extracts
    const int jown = w * 32 + (l & 31);   // owned output (lanes 32-63 duplicate)

    __shared__ __align__(16) _Float16 s_hhi[2][HH];      // h_hi operand, dbuf
    __shared__ __align__(16) _Float16 s_hlo[2][HH];      // h_lo*2048 operand, dbuf
    __shared__ __align__(16) float    s_xp[2][16 * XPLD];// xproj chunk, dbuf
    __shared__ float s_hf[HH];                           // final h fp32 (heads)
    __shared__ int s_flag;

    // ---- storage-dtype detector (R3-proven; bf16 expected) ----
    if (tid == 0) {
        const unsigned short* p = (const unsigned short*)Whhv;
        int cnt = 0;
        for (int i = 0; i < 256; ++i) { int e = (p[i] >> 7) & 0xFF; cnt += (e > 128) ? 1 : 0; }
        s_flag = (cnt > 16) ? 1 : 0;   // 1 => fp32 storage
    }
    __syncthreads();
    const bool f32io = (s_flag != 0);

    // ---- B-fragments, register-stationary, f16 (bf16->f16 exact) ----
    // bfrag[c*2+t]: lane holds W(j, k0..k0+7), j = w*32 + t*16 + col,
    // k0 = 32c + quad*8.  c 0..7: W_hh (k<256); c 8..11: W_ih (xproj chunks).
    f16x8 bfrag[24];
#pragma unroll
    for (int c = 0; c < 12; ++c) {
#pragma unroll
        for (int t = 0; t < 2; ++t) {
            const int j  = w * 32 + t * 16 + col;
            const int k0 = 32 * c + quad * 8;
            f16x8 bv;
            if (!f32io) {
                const unsigned short* src = (k0 < HH)
                    ? ((const unsigned short*)Whhv + j * HH + k0)
                    : ((const unsigned short*)Wihv + j * II + (k0 - HH));
                ushort8_t u = *(const ushort8_t*)src;
#pragma unroll
                for (int e = 0; e < 8; ++e) bv[e] = (_Float16)bf2f(u[e]);
            } else {
                const float* src = (k0 < HH)
                    ? ((const float*)Whhv + j * HH + k0)
                    : ((const float*)Wihv + j * II + (k0 - HH));
#pragma unroll
                for (int e = 0; e < 8; ++e) bv[e] = (_Float16)src[e];
            }
            bfrag[c * 2 + t] = bv;
        }
    }

    const f32x4 kz = {0.f, 0.f, 0.f, 0.f};

    // ---- xproj chunk-prep machinery ----
    // A-frag layout: row m = lane&15 (= timestep-in-chunk), k = (lane>>4)*8+e.
    ushort8_t xru[4];   // raw bf16 prefetch
    float4_t  xrf[8];   // raw fp32 prefetch
    f16x8     xaf[4];   // converted A-frags

    auto xload = [&](int tbase) {
        if (!f32io) {
            const unsigned short* gp = (const unsigned short*)xv
                + ((size_t)b * TT + tbase + col) * II + quad * 8;
#pragma unroll
            for (int c = 0; c < 4; ++c) xru[c] = *(const ushort8_t*)(gp + 32 * c);
        } else {
            const float* gp = (const float*)xv
                + ((size_t)b * TT + tbase + col) * II + quad * 8;
#pragma unroll
            for (int c = 0; c < 4; ++c) {
                xrf[2 * c]     = *(const float4_t*)(gp + 32 * c);
                xrf[2 * c + 1] = *(const float4_t*)(gp + 32 * c + 4);
            }
        }
    };
    auto xcvt = [&]() {
        if (!f32io) {
#pragma unroll
            for (int c = 0; c < 4; ++c)
#pragma unroll
                for (int e = 0; e < 8; ++e) xaf[c][e] = (_Float16)bf2f(xru[c][e]);
        } else {
#pragma unroll
            for (int c = 0; c < 4; ++c)
#pragma unroll
                for (int e = 0; e < 8; ++e) xaf[c][e] = (_Float16)xrf[2 * c + (e >> 2)][e & 3];
        }
    };
    auto xmm = [&](float* dst) {
        f32x4 xa[2];
        xa[0] = kz; xa[1] = kz;
#pragma unroll
        for (int c = 0; c < 4; ++c)
#pragma unroll
            for (int tt = 0; tt < 2; ++tt)
                xa[tt] = __builtin_amdgcn_mfma_f32_16x16x32_f16(xaf[c], bfrag[(8 + c) * 2 + tt], xa[tt], 0, 0, 0);
        // D layout: col = lane&15 (-> j), row = (lane>>4)*4 + r (-> t')
#pragma unroll
        for (int tt = 0; tt < 2; ++tt)
#pragma unroll
            for (int r = 0; r < 4; ++r)
                dst[(quad * 4 + r) * XPLD + w * 32 + tt * 16 + col] = xa[tt][r];
    };

    // ---- init h (fp32 state; publish hi/lo operand) ----
    float hreg;
    {
        if (!f32io) hreg = bf2f(((const unsigned short*)hxv)[b * HH + jown]);
        else        hreg = ((const float*)hxv)[b * HH + jown];
        _Float16 hi = (_Float16)hreg;
        _Float16 lo = (_Float16)((hreg - (float)hi) * 2048.f);
        s_hhi[0][jown] = hi;      // duplicate lanes write identical values
        s_hlo[0][jown] = lo;
    }

    // ---- prologue: xproj for chunk 0 ----
    xload(0); xcvt(); xmm(&s_xp[0][0]);
    __syncthreads();

    for (int t = 0; t < TT; ++t) {
        const int par   = t & 1;
        const int slot  = (t >> 4) & 1;
        const int slice = t & 15;
        const int tn    = (t & ~15) + 16;       // next chunk base
        const bool prep = (tn < TT);

        // chunk n+1 prep pipeline: load @slice0, cvt @slice4 (vmcnt slack ~4
        // steps), mfma+store @slice8 (stores land well before chunk turnover)
        if (slice == 0 && prep) xload(tn);

        const float xp = s_xp[slot][slice * XPLD + jown];

        const _Float16* hbh = s_hhi[par];
        const _Float16* hbl = s_hlo[par];

        if (slice == 4 && prep) xcvt();
        if (slice == 8 && prep) xmm(&s_xp[slot ^ 1][0]);

        f32x4 acch[2], accl[2];
        {   // c = 0, seed with persistent zero
            f16x8 a = *(const f16x8*)(hbh + quad * 8);
            acch[0] = __builtin_amdgcn_mfma_f32_16x16x32_f16(a, bfrag[0], kz, 0, 0, 0);
            acch[1] = __builtin_amdgcn_mfma_f32_16x16x32_f16(a, bfrag[1], kz, 0, 0, 0);
        }
#pragma unroll
        for (int c = 1; c < 8; ++c) {           // h_hi part: k = 32c + quad*8
            f16x8 a = *(const f16x8*)(hbh + 32 * c + quad * 8);
            acch[0] = __builtin_amdgcn_mfma_f32_16x16x32_f16(a, bfrag[c * 2 + 0], acch[0], 0, 0, 0);
            acch[1] = __builtin_amdgcn_mfma_f32_16x16x32_f16(a, bfrag[c * 2 + 1], acch[1], 0, 0, 0);
        }
        {   // lo, c = 0
            f16x8 a = *(const f16x8*)(hbl + quad * 8);
            accl[0] = __builtin_amdgcn_mfma_f32_16x16x32_f16(a, bfrag[0], kz, 0, 0, 0);
            accl[1] = __builtin_amdgcn_mfma_f32_16x16x32_f16(a, bfrag[1], kz, 0, 0, 0);
        }
#pragma unroll
        for (int c = 1; c < 8; ++c) {           // h_lo part (same weights)
            f16x8 a = *(const f16x8*)(hbl + 32 * c + quad * 8);
            accl[0] = __builtin_amdgcn_mfma_f32_16x16x32_f16(a, bfrag[c * 2 + 0], accl[0], 0, 0, 0);
            accl[1] = __builtin_amdgcn_mfma_f32_16x16x32_f16(a, bfrag[c * 2 + 1], accl[1], 0, 0, 0);
        }

        // all 16 D-rows identical; lane takes its tile's reg 0 at its col
        float ph = tsel ? acch[1][0] : acch[0][0];
        float pl = tsel ? accl[1][0] : accl[0][0];
        float pre = (ph + xp) + pl * (1.f / 2048.f);   // same order as R1 (absmax-proven)

        hreg = 0.8f * hreg + 0.2f * fmaxf(pre, 0.f);

        _Float16 hi = (_Float16)hreg;
        _Float16 lo = (_Float16)((hreg - (float)hi) * 2048.f);
        s_hhi[par ^ 1][jown] = hi;              // duplicate lanes: same value, same addr
        s_hlo[par ^ 1][jown] = lo;

        if (t == TT - 1) s_hf[jown] = hreg;     // publish fp32 h for heads
        __syncthreads();
    }

    // ---- epilogue ----
    // new_hx: out[2304 + b*256 + j] (fp32 state)
    if (l < 32) {
        if (!f32io) ((__hip_bfloat16*)outv)[2304 + b * HH + jown] = __float2bfloat16(hreg);
        else        ((float*)outv)[2304 + b * HH + jown] = hreg;
    }

    // actor_logits out[b*8 + a], critic out[2048 + b]
    if (tid < 9) {
        float acc = 0.f;
        if (!f32io) {
            const unsigned short* wr = (tid < 8) ? ((const unsigned short*)Wactv + tid * HH)
                                                 : (const unsigned short*)Wcritv;
            for (int i = 0; i < HH; ++i) acc += bf2f(wr[i]) * s_hf[i];
        } else {
            const float* wr = (tid < 8) ? ((const float*)Wactv + tid * HH)
                                        : (const float*)Wcritv;
            for (int i = 0; i < HH; ++i) acc += wr[i] * s_hf[i];
        }
        const int idx = (tid < 8) ? (b * 8 + tid) : (2048 + b);
        if (!f32io) ((__hip_bfloat16*)outv)[idx] = __float2bfloat16(acc);
        else        ((float*)outv)[idx] = acc;
    }
}

extern "C" void kernel_launch(void* const* d_in, const int* in_sizes, int n_in,
                              void* d_out, int out_size, void* d_ws, size_t ws_size,
                              hipStream_t stream) {
    // dict order: x [256,2048,128], hx [1,256,256], W_ih [256,128],
    //             W_hh [256,256], W_actor [8,256], W_critic [1,256]
    rnn_mfma_w8<<<dim3(BB), dim3(512), 0, stream>>>(
        d_in[0], d_in[1], d_in[2], d_in[3], d_in[4], d_in[5], d_out);
}

// Round 3
// 1596.832 us; speedup vs baseline: 1.6133x; 1.3658x over previous
//
#include <hip/hip_runtime.h>
#include <hip/hip_bf16.h>
#include <stdint.h>

// ContinuousActorCritic: B=256, T=2048, I=128, H=256, A=8
#define BB 256
#define TT 2048
#define II 128
#define HH 256
#define XPLD 260   // s_xp row stride (floats); 256+4 pad keeps write conflicts at free 2-way

typedef _Float16       f16x8     __attribute__((ext_vector_type(8)));  // 4 VGPR
typedef float          f32x4     __attribute__((ext_vector_type(4)));
typedef unsigned short ushort8_t __attribute__((ext_vector_type(8)));
typedef float          float4_t  __attribute__((ext_vector_type(4)));

__device__ __forceinline__ float bf2f(unsigned short u) {
    union { unsigned int i; float f; } v; v.i = ((unsigned int)u) << 16; return v.f;
}

// R3: hi/lo precision split carried in MFMA A-ROWS instead of two chains.
// R2 post-mortem (cycle model, validated against MfmaUtil): 16x16x32-f16 MFMA
// occupies a SIMD matrix pipe ~16 cy (2.5PF/1024 SIMD). R2 paid 66 MFMA/SIMD/
// step (1056 cy) + 131 KB/step LDS A-operand re-reads (~1030 cy on the
// 128 B/cy CU return bus), largely serial -> 2480 cy/step.
// Fix: A rows %4==0 carry h_hi, rows %4==1 carry h_lo*2048 (rows are
// INDEPENDENT dot products -> acc reg0 = hi result, reg1 = lo result,
// bit-identical to separate chains; rows 2,3 are garbage landing in ignored
// regs 2,3). One MFMA + one ds_read where R2 used two of each:
// 33 MFMA/SIMD/step (528 cy) + 66 KB/step LDS (~530 cy).
// Wave w owns outputs [w*32, w*32+32) as 2 N-tiles; 8 waves = 2/SIMD.
// xproj batched per 16-step chunk via MFMA M-dim = timesteps (load@0, cvt@4,
// mfma@8 of each chunk), staged to s_xp dbuf, consumed as 1 fp32 read/step.
__global__ __launch_bounds__(512, 2)
void rnn_mfma_row2(const void* __restrict__ xv,  const void* __restrict__ hxv,
                   const void* __restrict__ Wihv, const void* __restrict__ Whhv,
                   const void* __restrict__ Wactv, const void* __restrict__ Wcritv,
                   void* __restrict__ outv)
{
    const int b    = blockIdx.x;
    const int tid  = threadIdx.x;
    const int w    = tid >> 6;            // 0..7
    const int l    = tid & 63;
    const int quad = l >> 4;
    const int col  = l & 15;
    const int tsel = (l >> 4) & 1;        // which N-tile this lane extracts
    const int jown = w * 32 + (l & 31);   // owned output (lanes 32-63 duplicate)
    const int aoff = ((l & 3) == 1) ? 256 : 0;  // A-row%4==1 lanes feed the lo half

    __shared__ __align__(16) _Float16 s_h[2][512];       // [k]=h_hi, [256+k]=h_lo*2048; dbuf
    __shared__ __align__(16) float    s_xp[2][16 * XPLD];// xproj chunk, dbuf
    __shared__ float s_hf[HH];                           // final h fp32 (heads)
    __shared__ int s_flag;

    // ---- storage-dtype detector (R3-proven; bf16 expected) ----
    if (tid == 0) {
        const unsigned short* p = (const unsigned short*)Whhv;
        int cnt = 0;
        for (int i = 0; i < 256; ++i) { int e = (p[i] >> 7) & 0xFF; cnt += (e > 128) ? 1 : 0; }
        s_flag = (cnt > 16) ? 1 : 0;   // 1 => fp32 storage
    }
    __syncthreads();
    const bool f32io = (s_flag != 0);

    // ---- B-fragments, register-stationary, f16 (bf16->f16 exact) ----
    // bfrag[c*2+t]: lane holds W(j, k0..k0+7), j = w*32 + t*16 + col,
    // k0 = 32c + quad*8.  c 0..7: W_hh; c 8..11: W_ih (xproj chunks).
    f16x8 bfrag[24];
#pragma unroll
    for (int c = 0; c < 12; ++c) {
#pragma unroll
        for (int t = 0; t < 2; ++t) {
            const int j  = w * 32 + t * 16 + col;
            const int k0 = 32 * c + quad * 8;
            f16x8 bv;
            if (!f32io) {
                const unsigned short* src = (k0 < HH)
                    ? ((const unsigned short*)Whhv + j * HH + k0)
                    : ((const unsigned short*)Wihv + j * II + (k0 - HH));
                ushort8_t u = *(const ushort8_t*)src;
#pragma unroll
                for (int e = 0; e < 8; ++e) bv[e] = (_Float16)bf2f(u[e]);
            } else {
                const float* src = (k0 < HH)
                    ? ((const float*)Whhv + j * HH + k0)
                    : ((const float*)Wihv + j * II + (k0 - HH));
#pragma unroll
                for (int e = 0; e < 8; ++e) bv[e] = (_Float16)src[e];
            }
            bfrag[c * 2 + t] = bv;
        }
    }

    const f32x4 kz = {0.f, 0.f, 0.f, 0.f};

    // ---- xproj chunk-prep machinery ----
    // A-frag layout: row m = lane&15 (= timestep-in-chunk), k = (lane>>4)*8+e.
    ushort8_t xru[4];   // raw bf16 prefetch
    float4_t  xrf[8];   // raw fp32 prefetch
    f16x8     xaf[4];   // converted A-frags

    auto xload = [&](int tbase) {
        if (!f32io) {
            const unsigned short* gp = (const unsigned short*)xv
                + ((size_t)b * TT + tbase + col) * II + quad * 8;
#pragma unroll
            for (int c = 0; c < 4; ++c) xru[c] = *(const ushort8_t*)(gp + 32 * c);
        } else {
            const float* gp = (const float*)xv
                + ((size_t)b * TT + tbase + col) * II + quad * 8;
#pragma unroll
            for (int c = 0; c < 4; ++c) {
                xrf[2 * c]     = *(const float4_t*)(gp + 32 * c);
                xrf[2 * c + 1] = *(const float4_t*)(gp + 32 * c + 4);
            }
        }
    };
    auto xcvt = [&]() {
        if (!f32io) {
#pragma unroll
            for (int c = 0; c < 4; ++c)
#pragma unroll
                for (int e = 0; e < 8; ++e) xaf[c][e] = (_Float16)bf2f(xru[c][e]);
        } else {
#pragma unroll
            for (int c = 0; c < 4; ++c)
#pragma unroll
                for (int e = 0; e < 8; ++e) xaf[c][e] = (_Float16)xrf[2 * c + (e >> 2)][e & 3];
        }
    };
    auto xmm = [&](float* dst) {
        f32x4 xa[2];
        xa[0] = kz; xa[1] = kz;
#pragma unroll
        for (int c = 0; c < 4; ++c)
#pragma unroll
            for (int tt = 0; tt < 2; ++tt)
                xa[tt] = __builtin_amdgcn_mfma_f32_16x16x32_f16(xaf[c], bfrag[(8 + c) * 2 + tt], xa[tt], 0, 0, 0);
        // D layout: col = lane&15 (-> j), row = (lane>>4)*4 + r (-> t')
#pragma unroll
        for (int tt = 0; tt < 2; ++tt)
#pragma unroll
            for (int r = 0; r < 4; ++r)
                dst[(quad * 4 + r) * XPLD + w * 32 + tt * 16 + col] = xa[tt][r];
    };

    // ---- init h (fp32 state; publish hi/lo operand halves) ----
    float hreg;
    {
        if (!f32io) hreg = bf2f(((const unsigned short*)hxv)[b * HH + jown]);
        else        hreg = ((const float*)hxv)[b * HH + jown];
        _Float16 hi = (_Float16)hreg;
        _Float16 lo = (_Float16)((hreg - (float)hi) * 2048.f);
        s_h[0][jown]       = hi;   // duplicate lanes write identical values
        s_h[0][256 + jown] = lo;
    }

    // ---- prologue: xproj for chunk 0 ----
    xload(0); xcvt(); xmm(&s_xp[0][0]);
    __syncthreads();

    for (int t = 0; t < TT; ++t) {
        const int par   = t & 1;
        const int slot  = (t >> 4) & 1;
        const int slice = t & 15;
        const int tn    = (t & ~15) + 16;       // next chunk base
        const bool prep = (tn < TT);

        // chunk n+1 prep pipeline: load @slice0, cvt @slice4, mfma+store @slice8
        if (slice == 0 && prep) xload(tn);

        const float xp = s_xp[slot][slice * XPLD + jown];

        const _Float16* hb = s_h[par];

        if (slice == 4 && prep) xcvt();
        if (slice == 8 && prep) xmm(&s_xp[slot ^ 1][0]);

        // recurrence MFMAs: one read + one MFMA per K-chunk covers hi AND lo
        // (hi rides A-rows %4==0 -> acc reg0; lo rides rows %4==1 -> reg1)
        f32x4 acc0, acc1;
        {   // c = 0, seed with persistent zero
            f16x8 a = *(const f16x8*)(hb + aoff + quad * 8);
            acc0 = __builtin_amdgcn_mfma_f32_16x16x32_f16(a, bfrag[0], kz, 0, 0, 0);
            acc1 = __builtin_amdgcn_mfma_f32_16x16x32_f16(a, bfrag[1], kz, 0, 0, 0);
        }
#pragma unroll
        for (int c = 1; c < 8; ++c) {
            f16x8 a = *(const f16x8*)(hb + aoff + 32 * c + quad * 8);
            acc0 = __builtin_amdgcn_mfma_f32_16x16x32_f16(a, bfrag[c * 2 + 0], acc0, 0, 0, 0);
            acc1 = __builtin_amdgcn_mfma_f32_16x16x32_f16(a, bfrag[c * 2 + 1], acc1, 0, 0, 0);
        }

        // lane (any quad) holds D rows 4q (hi) and 4q+1 (lo) at its col
        float ph = tsel ? acc1[0] : acc0[0];
        float pl = tsel ? acc1[1] : acc0[1];
        float pre = (ph + xp) + pl * (1.f / 2048.f);   // same order as R2 (absmax-proven)

        hreg = 0.8f * hreg + 0.2f * fmaxf(pre, 0.f);

        _Float16 hi = (_Float16)hreg;
        _Float16 lo = (_Float16)((hreg - (float)hi) * 2048.f);
        s_h[par ^ 1][jown]       = hi;          // duplicate lanes: same value, same addr
        s_h[par ^ 1][256 + jown] = lo;

        if (t == TT - 1) s_hf[jown] = hreg;     // publish fp32 h for heads
        __syncthreads();
    }

    // ---- epilogue ----
    // new_hx: out[2304 + b*256 + j] (fp32 state)
    if (l < 32) {
        if (!f32io) ((__hip_bfloat16*)outv)[2304 + b * HH + jown] = __float2bfloat16(hreg);
        else        ((float*)outv)[2304 + b * HH + jown] = hreg;
    }

    // actor_logits out[b*8 + a], critic out[2048 + b]
    if (tid < 9) {
        float acc = 0.f;
        if (!f32io) {
            const unsigned short* wr = (tid < 8) ? ((const unsigned short*)Wactv + tid * HH)
                                                 : (const unsigned short*)Wcritv;
            for (int i = 0; i < HH; ++i) acc += bf2f(wr[i]) * s_hf[i];
        } else {
            const float* wr = (tid < 8) ? ((const float*)Wactv + tid * HH)
                                        : (const float*)Wcritv;
            for (int i = 0; i < HH; ++i) acc += wr[i] * s_hf[i];
        }
        const int idx = (tid < 8) ? (b * 8 + tid) : (2048 + b);
        if (!f32io) ((__hip_bfloat16*)outv)[idx] = __float2bfloat16(acc);
        else        ((float*)outv)[idx] = acc;
    }
}

extern "C" void kernel_launch(void* const* d_in, const int* in_sizes, int n_in,
                              void* d_out, int out_size, void* d_ws, size_t ws_size,
                              hipStream_t stream) {
    // dict order: x [256,2048,128], hx [1,256,256], W_ih [256,128],
    //             W_hh [256,256], W_actor [8,256], W_critic [1,256]
    rnn_mfma_row2<<<dim3(BB), dim3(512), 0, stream>>>(
        d_in[0], d_in[1], d_in[2], d_in[3], d_in[4], d_in[5], d_out);
}